// Round 1
// baseline (125.459 us; speedup 1.0000x reference)
//
#include <hip/hip_runtime.h>

#define BATCH 256
#define H 64
#define W 64
#define NPAT 16
#define HW (H * W)

// One kernel per layer. Block = 256 threads = 4 b-lanes x 64 w, fixed h.
// Grid = (64 h, 16 b-chunks); each block handles 16 consecutive b.
// tw tile (16 patterns x 64 w for this h) staged in LDS with sigmoid applied.
template <int REG>
__global__ __launch_bounds__(256) void layer_kernel(
    const float* __restrict__ prev,      // [256][64][64] previous outputs
    const float* __restrict__ tg_layer,  // [16][64][64] raw toggle gates for this layer
    float* __restrict__ out,             // [256][64][64]
    double* __restrict__ reg_acc)        // single accumulator
{
    __shared__ float tws[NPAT][W];
    const int tid = threadIdx.x;
    const int h = blockIdx.x;
    const int bchunk = blockIdx.y;

    // Stage sigmoid(tg) tile: 1024 floats, 4 per thread, coalesced.
#pragma unroll
    for (int k = 0; k < 4; ++k) {
        int idx = tid + k * 256;
        int p = idx >> 6, w = idx & 63;
        float g = tg_layer[(p * H + h) * W + w];
        tws[p][w] = 1.0f / (1.0f + __expf(-g));
    }
    __syncthreads();

    const int w = tid & 63;
    const int bl = tid >> 6;
    const int base = h * W + w;
    float racc = 0.0f;

#pragma unroll
    for (int bi = 0; bi < 4; ++bi) {
        int b = bchunk * 16 + bi * 4 + bl;
        // SHIFTS = (0,1,1,2) along batch; v for shift 1 is shared by j=1,2.
        float v0 = prev[b * HW + base];
        float v1 = prev[((b + 1) & 255) * HW + base];
        float v3 = prev[((b + 2) & 255) * HW + base];
        float a0 = 1.0f - v0, a1 = 1.0f - v1, a3 = 1.0f - v3;

        // bits[p] = (p>>3, p>>2, p>>1, p>>0) & 1 for j = 0,1,2,3
        float f0[2] = {a0, v0};
        float f1[2] = {a1, v1};
        float f3[2] = {a3, v3};

        float wp[NPAT];
        float acc = 0.0f;
#pragma unroll
        for (int p = 0; p < NPAT; ++p) {
            float t = f0[(p >> 3) & 1];
            t *= f1[(p >> 2) & 1];
            t *= f1[(p >> 1) & 1];
            t *= f3[p & 1];
            wp[p] = t;
            acc += t * tws[p][w];
        }

        float o = fminf(fmaxf(acc, 0.0f), 1.0f);
        out[b * HW + base] = o;

        if (REG) {
            // sum_p log(w_p) = 8 * sum_j [log v_j + log(1-v_j)], with v1 counted twice
            float s = 8.0f * (__logf(v0) + __logf(a0) +
                              2.0f * (__logf(v1) + __logf(a1)) +
                              __logf(v3) + __logf(a3));
#pragma unroll
            for (int p = 0; p < NPAT; ++p) s += __logf(1.0f - wp[p]);
            racc += s;
        }
    }

    if (REG) {
        // wave(64) shuffle reduce, then 4 waves via LDS, one f64 atomic per block
#pragma unroll
        for (int off = 32; off; off >>= 1) racc += __shfl_down(racc, off, 64);
        __shared__ float wsum[4];
        if ((tid & 63) == 0) wsum[tid >> 6] = racc;
        __syncthreads();
        if (tid == 0) {
            float tot = wsum[0] + wsum[1] + wsum[2] + wsum[3];
            atomicAdd(reg_acc, (double)tot);
        }
    }
}

__global__ void finalize_kernel(const double* __restrict__ acc,
                                float* __restrict__ out_reg)
{
    // reg = -sum/(256*64*64*16), output reg/3
    *out_reg = (float)(-(*acc) / (16777216.0 * 3.0));
}

extern "C" void kernel_launch(void* const* d_in, const int* in_sizes, int n_in,
                              void* d_out, int out_size, void* d_ws, size_t ws_size,
                              hipStream_t stream)
{
    const float* x  = (const float*)d_in[0];                  // (256,64,64)
    const float* tg = (const float*)d_in[1];                  // (4,16,64,64)
    float* out   = (float*)d_out;                             // 1048576 + 1
    float* bufA  = (float*)d_ws;                              // 4 MB ping buffer
    double* acc  = (double*)((char*)d_ws + (size_t)BATCH * HW * sizeof(float));

    hipMemsetAsync(acc, 0, sizeof(double), stream);

    dim3 grid(H, 16);
    dim3 block(256);
    const size_t layer_stride = (size_t)NPAT * HW;

    // L0: x -> bufA (no reg; x may contain exact zeros)
    layer_kernel<0><<<grid, block, 0, stream>>>(x,    tg + 0 * layer_stride, bufA, acc);
    // L1: bufA -> d_out (reg)
    layer_kernel<1><<<grid, block, 0, stream>>>(bufA, tg + 1 * layer_stride, out,  acc);
    // L2: d_out -> bufA (reg)
    layer_kernel<1><<<grid, block, 0, stream>>>(out,  tg + 2 * layer_stride, bufA, acc);
    // L3: bufA -> d_out (reg)
    layer_kernel<1><<<grid, block, 0, stream>>>(bufA, tg + 3 * layer_stride, out,  acc);

    finalize_kernel<<<1, 1, 0, stream>>>(acc, out + (size_t)BATCH * HW);
}

// Round 3
// 72.099 us; speedup vs baseline: 1.7401x; 1.7401x over previous
//
#include <hip/hip_runtime.h>

#define BATCH 256
#define HWSZ  4096          // 64*64
#define COLS  16            // (h,w) columns per block
#define BSTR  17            // LDS row stride (+1 pad -> 2-way conflicts only, free)

// One block = 16 (h,w) columns x full batch of 256, ALL 4 layers fused.
// Columns are independent because the roll is along batch only.
// Thread (brow=tid>>4, c=tid&15) walks b = brow*16 .. brow*16+15 sequentially,
// keeping v[b],v[b+1] in registers (1 new LDS read per element).
__global__ __launch_bounds__(256) void fused_kernel(
    const float* __restrict__ x,         // [256][4096]
    const float* __restrict__ tg,        // [4][16][4096]
    float* __restrict__ out,             // [256][4096]
    float* __restrict__ partials)        // [256] per-block reg sums
{
    __shared__ float bufA[BATCH * BSTR];
    __shared__ float bufB[BATCH * BSTR];
    __shared__ float tws[64 * COLS];     // sigmoid(tg): 4 layers * 16 patterns
    __shared__ float wsum[4];

    const int tid  = threadIdx.x;
    const int hw0  = blockIdx.x * COLS;
    const int c    = tid & 15;
    const int brow = tid >> 4;
    const int b0   = brow * 16;

    // Stage sigmoid(tg): 4*16*16 = 1024 floats
#pragma unroll
    for (int k = 0; k < 4; ++k) {
        int idx = tid + k * 256;
        int c2 = idx & 15;
        int lp = idx >> 4;               // l*16 + p
        float g = tg[lp * HWSZ + hw0 + c2];
        tws[lp * COLS + c2] = 1.0f / (1.0f + __expf(-g));
    }

    // Stage x tile -> bufA (256 b x 16 c = 4096 floats, 16 iters x 256 thr)
#pragma unroll
    for (int k = 0; k < 16; ++k) {
        int idx = tid + k * 256;
        int b = idx >> 4;
        int c2 = idx & 15;
        bufA[b * BSTR + c2] = x[b * HWSZ + hw0 + c2];
    }

    float racc = 0.0f;
    float* src = bufA;
    float* dst = bufB;

#pragma unroll
    for (int l = 0; l < 4; ++l) {
        __syncthreads();

        // Per-layer sigmoid weights for this column; patterns 2/4, 3/5, 10/12,
        // 11/13 share identical w_p (j=1,j=2 both use v[b+1]) -> pre-sum.
        const float* tl = &tws[l * 16 * COLS + c];
        float T0  = tl[0 * COLS], T1 = tl[1 * COLS];
        float T24 = tl[2 * COLS] + tl[4 * COLS];
        float T35 = tl[3 * COLS] + tl[5 * COLS];
        float T6  = tl[6 * COLS], T7 = tl[7 * COLS];
        float T8  = tl[8 * COLS], T9 = tl[9 * COLS];
        float TAC = tl[10 * COLS] + tl[12 * COLS];
        float TBD = tl[11 * COLS] + tl[13 * COLS];
        float TE  = tl[14 * COLS], TF = tl[15 * COLS];

        float v0 = src[b0 * BSTR + c];
        float v1 = src[(b0 + 1) * BSTR + c];

#pragma unroll
        for (int k = 0; k < 16; ++k) {
            float v2 = src[((b0 + k + 2) & 255) * BSTR + c];
            float a0 = 1.0f - v0, a1 = 1.0f - v1, a2 = 1.0f - v2;

            float g0 = a1 * a1, g1 = a1 * v1, g2 = v1 * v1;
            float u00 = a0 * g0, u01 = a0 * g1, u02 = a0 * g2;
            float u10 = v0 * g0, u11 = v0 * g1, u12 = v0 * g2;

            float w0 = u00 * a2, w1 = u00 * v2;
            float w2 = u01 * a2, w3 = u01 * v2;   // == patterns 4,5
            float w6 = u02 * a2, w7 = u02 * v2;
            float w8 = u10 * a2, w9 = u10 * v2;
            float wA = u11 * a2, wB = u11 * v2;   // == patterns 12,13
            float wE = u12 * a2, wF = u12 * v2;

            float acc = w0 * T0 + w1 * T1 + w2 * T24 + w3 * T35
                      + w6 * T6 + w7 * T7 + w8 * T8 + w9 * T9
                      + wA * TAC + wB * TBD + wE * TE + wF * TF;
            float o = fminf(fmaxf(acc, 0.0f), 1.0f);

            if (l == 3) out[(b0 + k) * HWSZ + hw0 + c] = o;
            else        dst[(b0 + k) * BSTR + c] = o;

            if (l >= 1) {
                // sum_p log(w_p)    = 8 * log(v0*a0 * (v1*a1)^2 * v2*a2)
                // sum_p log(1-w_p)  = log( prod_p (1-w_p) ), dups squared
                float s1 = (1.0f - w0) * (1.0f - w1) * (1.0f - w6) * (1.0f - w7)
                         * (1.0f - w8) * (1.0f - w9) * (1.0f - wE) * (1.0f - wF);
                float s2 = (1.0f - w2) * (1.0f - w3) * (1.0f - wA) * (1.0f - wB);
                float pB = s1 * s2 * s2;
                float pA = (v0 * a0) * (g1 * g1) * (v2 * a2);
                racc += 8.0f * __logf(pA) + __logf(pB);
            }
            v0 = v1; v1 = v2;
        }
        float* t = src; src = dst; dst = t;
    }

    // Block reduction: wave shuffle (64) then cross-wave via LDS
#pragma unroll
    for (int off = 32; off; off >>= 1) racc += __shfl_down(racc, off, 64);
    if ((tid & 63) == 0) wsum[tid >> 6] = racc;
    __syncthreads();
    if (tid == 0) partials[blockIdx.x] = wsum[0] + wsum[1] + wsum[2] + wsum[3];
}

__global__ void finalize_kernel(const float* __restrict__ partials,
                                float* __restrict__ out_reg)
{
    int tid = threadIdx.x;                 // 256 threads
    double v = (double)partials[tid];
#pragma unroll
    for (int off = 32; off; off >>= 1) v += __shfl_down(v, off, 64);
    __shared__ double ws[4];
    if ((tid & 63) == 0) ws[tid >> 6] = v;
    __syncthreads();
    if (tid == 0) {
        double tot = ws[0] + ws[1] + ws[2] + ws[3];
        // reg = -(sum of logs)/(256*64*64*16), output reg/3
        out_reg[0] = (float)(-tot / (16777216.0 * 3.0));
    }
}

extern "C" void kernel_launch(void* const* d_in, const int* in_sizes, int n_in,
                              void* d_out, int out_size, void* d_ws, size_t ws_size,
                              hipStream_t stream)
{
    const float* x  = (const float*)d_in[0];   // (256,64,64)
    const float* tg = (const float*)d_in[1];   // (4,16,64,64)
    float* out      = (float*)d_out;           // 1048576 outputs + 1 reg
    float* partials = (float*)d_ws;            // 256 floats

    fused_kernel<<<dim3(HWSZ / COLS), dim3(256), 0, stream>>>(x, tg, out, partials);
    finalize_kernel<<<1, 256, 0, stream>>>(partials, out + (size_t)BATCH * HWSZ);
}